// Round 1
// baseline (249.679 us; speedup 1.0000x reference)
//
#include <hip/hip_runtime.h>

#define DIM 160
#define TH 16
#define TW 16
#define CD 40   // d-chunk per block; 160/40 = 4 chunks

// Fused LNCC: each block computes a TH x TW (h,w) tile, streaming d through a
// chunk of CD output slices. Per input slice z:
//   stage1: load (TH+8)x(TW+8) halo of x,y (clamped = edge padding), store the
//           5 pointwise products into LDS P.
//   stage2: 9-tap h-sum P -> T (register sliding window, 2 LDS reads/output).
//   stage3: 9-tap w-sum T -> ring[slot] (9-deep d-ring buffer).
//   stage4: per-thread running d-sum over ring (add new slot, subtract slot
//           leaving the window), then ncc math + accumulate when warmed up.
// Final: block reduce, one atomicAdd of -partial/8192000 into d_out (zeroed
// by hipMemsetAsync in kernel_launch).
__global__ __launch_bounds__(256, 2)
void lncc_kernel(const float* __restrict__ x, const float* __restrict__ y,
                 float* __restrict__ out)
{
    // padded strides chosen to keep worst-case bank aliasing ~2-way
    __shared__ float P[5][24][26];          // products, halo slice
    __shared__ float T[5][16][25];          // h-summed
    __shared__ float ring[9][5][16][17];    // hw-summed, 9-deep d ring
    __shared__ float wsum[4];

    const int t  = threadIdx.x;
    const int w0 = blockIdx.x * TW;
    const int h0 = blockIdx.y * TH;
    const int bz = blockIdx.z;
    const int b  = bz >> 2;                 // batch (0..1)
    const int d0 = (bz & 3) * CD;           // d-chunk origin

    const float* xb = x + (size_t)b * (DIM * DIM * DIM);
    const float* yb = y + (size_t)b * (DIM * DIM * DIM);

    const int i4 = t >> 4;                  // this thread's output (i,j)
    const int j4 = t & 15;

    float rs0 = 0.f, rs1 = 0.f, rs2 = 0.f, rs3 = 0.f, rs4 = 0.f;
    float acc = 0.f;

    for (int zi = d0 - 4; zi <= d0 + CD + 3; ++zi) {
        const int z = zi < 0 ? 0 : (zi > DIM - 1 ? DIM - 1 : zi);
        const float* xs = xb + (size_t)z * (DIM * DIM);
        const float* ys = yb + (size_t)z * (DIM * DIM);

        // ---- stage 1: halo load + products (576 positions / 256 threads) ----
        for (int p = t; p < 576; p += 256) {
            const int i = p / 24;
            const int j = p - i * 24;
            int gh = h0 - 4 + i; gh = gh < 0 ? 0 : (gh > DIM - 1 ? DIM - 1 : gh);
            int gw = w0 - 4 + j; gw = gw < 0 ? 0 : (gw > DIM - 1 ? DIM - 1 : gw);
            const float xv = xs[gh * DIM + gw];
            const float yv = ys[gh * DIM + gw];
            P[0][i][j] = xv;
            P[1][i][j] = yv;
            P[2][i][j] = xv * xv;
            P[3][i][j] = yv * yv;
            P[4][i][j] = xv * yv;
        }
        __syncthreads();

        // ---- stage 2: 9-tap h-sum, register sliding (240 threads) ----
        if (t < 240) {
            const int col  = t >> 1;
            const int half = t & 1;
            const int q  = col / 24;
            const int j  = col - q * 24;
            const int i0 = half * 8;
            float s = 0.f;
            #pragma unroll
            for (int k = 0; k < 9; ++k) s += P[q][i0 + k][j];
            T[q][i0][j] = s;
            #pragma unroll
            for (int u = 1; u < 8; ++u) {
                s += P[q][i0 + u + 8][j] - P[q][i0 + u - 1][j];
                T[q][i0 + u][j] = s;
            }
        }
        __syncthreads();

        // ---- stage 3: 9-tap w-sum into ring (160 threads) ----
        const int slot = (zi + 4) % 9;
        if (t < 160) {
            const int row  = t >> 1;
            const int half = t & 1;
            const int q  = row >> 4;
            const int i  = row & 15;
            const int j0 = half * 8;
            float s = 0.f;
            #pragma unroll
            for (int k = 0; k < 9; ++k) s += T[q][i][j0 + k];
            ring[slot][q][i][j0] = s;
            #pragma unroll
            for (int u = 1; u < 8; ++u) {
                s += T[q][i][j0 + u + 8] - T[q][i][j0 + u - 1];
                ring[slot][q][i][j0 + u] = s;
            }
        }
        __syncthreads();

        // ---- stage 4: d running sums + emit ----
        rs0 += ring[slot][0][i4][j4];
        rs1 += ring[slot][1][i4][j4];
        rs2 += ring[slot][2][i4][j4];
        rs3 += ring[slot][3][i4][j4];
        rs4 += ring[slot][4][i4][j4];
        if (zi >= d0 + 4) {
            const float inv = 1.0f / 729.0f;
            const float xm = rs0 * inv, ym = rs1 * inv;
            const float x2 = rs2 * inv, y2 = rs3 * inv, xy = rs4 * inv;
            const float cross = xy - xm * ym;
            const float vx = x2 - xm * xm;
            const float vy = y2 - ym * ym;
            acc += cross * cross / (vx * vy + 1e-5f);
            // subtract slice leaving the 9-window (slot about to be recycled)
            const int so = (zi - 4) % 9;
            rs0 -= ring[so][0][i4][j4];
            rs1 -= ring[so][1][i4][j4];
            rs2 -= ring[so][2][i4][j4];
            rs3 -= ring[so][3][i4][j4];
            rs4 -= ring[so][4][i4][j4];
        }
        // next iteration's post-stage1 barrier orders these reads before the
        // next ring write (which lands 2 barriers later)
    }

    // ---- block reduction: wave shuffle then cross-wave via LDS ----
    #pragma unroll
    for (int off = 32; off > 0; off >>= 1)
        acc += __shfl_down(acc, off, 64);
    const int wave = t >> 6;
    if ((t & 63) == 0) wsum[wave] = acc;
    __syncthreads();
    if (t == 0) {
        const float s = wsum[0] + wsum[1] + wsum[2] + wsum[3];
        atomicAdd(out, -s * (1.0f / 8192000.0f));
    }
}

extern "C" void kernel_launch(void* const* d_in, const int* in_sizes, int n_in,
                              void* d_out, int out_size, void* d_ws, size_t ws_size,
                              hipStream_t stream)
{
    const float* x = (const float*)d_in[0];
    const float* y = (const float*)d_in[1];
    float* out = (float*)d_out;

    // d_out is poisoned 0xAA before every call; we accumulate atomically
    hipMemsetAsync(out, 0, sizeof(float), stream);

    dim3 grid(DIM / TW, DIM / TH, 2 * (DIM / CD));  // 10 x 10 x 8 = 800 blocks
    lncc_kernel<<<grid, 256, 0, stream>>>(x, y, out);
}

// Round 2
// 201.107 us; speedup vs baseline: 1.2415x; 1.2415x over previous
//
#include <hip/hip_runtime.h>

#define DIM 160
#define SLICE (DIM * DIM)
#define TH 16
#define TW 16
#define CD 20   // output slices per block chunk; 160/20 = 8 chunks

// Fused LNCC, separable order d -> h -> w.
// Each 192-thread block owns a 16x16 (h,w) output tile and CD output slices.
//  - 144 "column" threads each own 4 consecutive-w columns of the 24x24 halo,
//    maintaining 5 running d-box-sums (x,y,x2,y2,xy) as float4 registers.
//    Advance: add products at clamp(z+5), subtract at clamp(z-4) (re-loaded
//    from global, L2/L3-served). No LDS ring buffer.
//  - Per output slice: write column sums S (b128) -> barrier -> 120 threads
//    do the 9-tap h-sum S->T with b128 sliding window; column threads overlap
//    their running-sum update here -> barrier -> 64 threads do the 9-tap
//    w-sum from T (3x b128 per channel, register slide) + ncc, accumulating
//    4 outputs each.
//  - Wave-0 shuffle reduction, one atomicAdd per block.
__global__ __launch_bounds__(192, 5)
void lncc_kernel(const float* __restrict__ x, const float* __restrict__ y,
                 float* __restrict__ out)
{
    __shared__ __align__(16) float S[5][24][28];   // column d-sums (halo slice)
    __shared__ __align__(16) float T[5][16][28];   // after h-sum

    const int t  = threadIdx.x;
    const int w0 = blockIdx.x * TW;
    const int h0 = blockIdx.y * TH;
    const int bz = blockIdx.z;
    const int b   = bz >> 3;              // batch
    const int zo0 = (bz & 7) * CD;        // first output slice of chunk

    const float* xb = x + (size_t)b * (DIM * SLICE);
    const float* yb = y + (size_t)b * (DIM * SLICE);

    // ---- stage1 role: column group (h, w4) ----
    const int h1  = t / 6;                // 0..31 (valid < 24 for t < 144)
    const int w41 = t - h1 * 6;           // 0..5
    const int gh  = min(max(h0 - 4 + h1, 0), DIM - 1);
    const int gwb = w0 - 4 + 4 * w41;
    const bool fast = (gwb >= 0) && (gwb + 3 < DIM);
    const int jc0 = min(max(gwb + 0, 0), DIM - 1);
    const int jc1 = min(max(gwb + 1, 0), DIM - 1);
    const int jc2 = min(max(gwb + 2, 0), DIM - 1);
    const int jc3 = min(max(gwb + 3, 0), DIM - 1);

    auto load4 = [&](const float* sl) -> float4 {
        const float* row = sl + (size_t)gh * DIM;
        if (fast) return *reinterpret_cast<const float4*>(row + gwb);
        float4 r;
        r.x = row[jc0]; r.y = row[jc1]; r.z = row[jc2]; r.w = row[jc3];
        return r;
    };

    float4 rs0 = {0,0,0,0}, rs1 = {0,0,0,0}, rs2 = {0,0,0,0},
           rs3 = {0,0,0,0}, rs4 = {0,0,0,0};

    // ---- warmup: build d-window [zo0-4, zo0+4] (clamped taps) ----
    if (t < 144) {
        #pragma unroll
        for (int k = -4; k <= 4; ++k) {
            const int z = min(max(zo0 + k, 0), DIM - 1);
            const float* xs = xb + (size_t)z * SLICE;
            const float* ys = yb + (size_t)z * SLICE;
            const float4 xv = load4(xs);
            const float4 yv = load4(ys);
            rs0 += xv; rs1 += yv;
            rs2 += xv * xv; rs3 += yv * yv; rs4 += xv * yv;
        }
    }

    // ---- stage2 role: (channel, w-group, row-quarter) ----
    const int c2  = t / 24;               // 0..4 for t < 120
    const int r2  = t - c2 * 24;
    const int w42 = r2 >> 2;              // 0..5
    const int i02 = (r2 & 3) * 4;         // 0,4,8,12

    // ---- stage3 role: (i, j-group) ----
    const int i3 = t >> 2;                // 0..15 for t < 64
    const int j3 = (t & 3) * 4;           // 0,4,8,12

    float acc = 0.f;

    for (int zo = zo0; zo < zo0 + CD; ++zo) {
        // stage1: publish column d-sums
        if (t < 144) {
            *reinterpret_cast<float4*>(&S[0][h1][4 * w41]) = rs0;
            *reinterpret_cast<float4*>(&S[1][h1][4 * w41]) = rs1;
            *reinterpret_cast<float4*>(&S[2][h1][4 * w41]) = rs2;
            *reinterpret_cast<float4*>(&S[3][h1][4 * w41]) = rs3;
            *reinterpret_cast<float4*>(&S[4][h1][4 * w41]) = rs4;
        }
        __syncthreads();

        // stage2: 9-tap h-sum (b128 column sliding)
        if (t < 120) {
            float4 s = {0,0,0,0};
            #pragma unroll
            for (int k = 0; k < 9; ++k)
                s += *reinterpret_cast<const float4*>(&S[c2][i02 + k][4 * w42]);
            *reinterpret_cast<float4*>(&T[c2][i02][4 * w42]) = s;
            #pragma unroll
            for (int m = 1; m < 4; ++m) {
                s += *reinterpret_cast<const float4*>(&S[c2][i02 + 8 + m][4 * w42])
                   - *reinterpret_cast<const float4*>(&S[c2][i02 + m - 1][4 * w42]);
                *reinterpret_cast<float4*>(&T[c2][i02 + m][4 * w42]) = s;
            }
        }

        // overlap: advance running d-sums for next output slice
        if (t < 144 && zo + 1 < zo0 + CD) {
            const int za = min(zo + 5, DIM - 1);
            const int zs = max(zo - 4, 0);
            const float* xsa = xb + (size_t)za * SLICE;
            const float* ysa = yb + (size_t)za * SLICE;
            const float* xss = xb + (size_t)zs * SLICE;
            const float* yss = yb + (size_t)zs * SLICE;
            const float4 xa = load4(xsa), ya = load4(ysa);
            const float4 xs_ = load4(xss), ys_ = load4(yss);
            rs0 += xa - xs_;
            rs1 += ya - ys_;
            rs2 += xa * xa - xs_ * xs_;
            rs3 += ya * ya - ys_ * ys_;
            rs4 += xa * ya - xs_ * ys_;
        }
        __syncthreads();

        // stage3: 9-tap w-sum (3x b128 per channel, register slide) + ncc
        if (t < 64) {
            float su[5][4];
            #pragma unroll
            for (int c = 0; c < 5; ++c) {
                const float4 t0 = *reinterpret_cast<const float4*>(&T[c][i3][j3]);
                const float4 t1 = *reinterpret_cast<const float4*>(&T[c][i3][j3 + 4]);
                const float4 t2 = *reinterpret_cast<const float4*>(&T[c][i3][j3 + 8]);
                float s = t0.x + t0.y + t0.z + t0.w + t1.x + t1.y + t1.z + t1.w + t2.x;
                su[c][0] = s;
                s += t2.y - t0.x; su[c][1] = s;
                s += t2.z - t0.y; su[c][2] = s;
                s += t2.w - t0.z; su[c][3] = s;
            }
            const float inv = 1.0f / 729.0f;
            #pragma unroll
            for (int m = 0; m < 4; ++m) {
                const float xm = su[0][m] * inv, ym = su[1][m] * inv;
                const float x2 = su[2][m] * inv, y2 = su[3][m] * inv;
                const float xy = su[4][m] * inv;
                const float cross = xy - xm * ym;
                const float vx = x2 - xm * xm;
                const float vy = y2 - ym * ym;
                acc += cross * cross / (vx * vy + 1e-5f);
            }
        }
        // next loop's post-stage1 barrier orders stage3 T-reads before the
        // next stage2 T-writes
    }

    // acc is nonzero only in wave 0 — shuffle-reduce and emit
    #pragma unroll
    for (int off = 32; off > 0; off >>= 1)
        acc += __shfl_down(acc, off, 64);
    if (t == 0)
        atomicAdd(out, -acc * (1.0f / 8192000.0f));
}

extern "C" void kernel_launch(void* const* d_in, const int* in_sizes, int n_in,
                              void* d_out, int out_size, void* d_ws, size_t ws_size,
                              hipStream_t stream)
{
    const float* x = (const float*)d_in[0];
    const float* y = (const float*)d_in[1];
    float* out = (float*)d_out;

    // d_out is poisoned 0xAA before every call; accumulate atomically on zero
    hipMemsetAsync(out, 0, sizeof(float), stream);

    dim3 grid(DIM / TW, DIM / TH, 2 * (DIM / CD));  // 10 x 10 x 16 = 1600 blocks
    lncc_kernel<<<grid, 192, 0, stream>>>(x, y, out);
}

// Round 3
// 163.504 us; speedup vs baseline: 1.5271x; 1.2300x over previous
//
#include <hip/hip_runtime.h>

#define DIM 160
#define SLICE (DIM * DIM)
#define TH 16
#define TW 16
#define CD 40   // output slices per block chunk; 160/CD = 4 chunks per batch

// Fused LNCC, separable order h -> w -> d, each input slice loaded ONCE.
// Per input slice z (48 per chunk):
//   stage1: 144 threads load 24x24 halo of x,y (clamped), write 5 product
//           planes to S (b128).
//   stage2: 120 threads 9-tap h-sum S->T (b128 register slide); global
//           prefetch of slice z+1 issued just before, consumed next iter.
//   stage3: 64 threads 9-tap w-sum T->U (b128 slide).
//   stage4: all 256 threads (one output (h,w) column each) update 5 running
//           d-sums from U, keeping a 9-deep per-channel history in REGISTERS
//           (compile-time ring phase via 9-unrolled z loop) -> no global
//           re-read for the subtraction, no LDS ring.
// LDS planes padded +8 words so channel stride != 0 mod 32 banks.
#define SIDX(c,i,j) ((c)*680 + (i)*28 + (j))   // S: 24x28 plane (+8 pad)
#define TIDX(c,i,j) ((c)*456 + (i)*28 + (j))   // T: 16x28 plane (+8 pad)
#define UIDX(c,i,j) ((c)*260 + (i)*16 + (j))   // U: 16x16 plane (+4 pad)

__global__ __launch_bounds__(256, 4)
void lncc_kernel(const float* __restrict__ x, const float* __restrict__ y,
                 float* __restrict__ out)
{
    __shared__ __align__(16) float S[5 * 680];
    __shared__ __align__(16) float T[5 * 456];
    __shared__ __align__(16) float U[5 * 260];
    __shared__ float wsum[4];

    const int t  = threadIdx.x;
    const int w0 = blockIdx.x * TW;
    const int h0 = blockIdx.y * TH;
    const int bz = blockIdx.z;
    const int b   = bz >> 2;              // batch
    const int zo0 = (bz & 3) * CD;        // first output slice of chunk

    const float* xb = x + (size_t)b * (DIM * SLICE);
    const float* yb = y + (size_t)b * (DIM * SLICE);

    // ---- stage1 role: halo column group (h1, w41) ----
    const int h1  = t / 6;                // 0..23 valid for t<144
    const int w41 = t - h1 * 6;           // 0..5
    const int gh  = min(max(h0 - 4 + h1, 0), DIM - 1);
    const int gwb = w0 - 4 + 4 * w41;
    const bool fast = (gwb >= 0) && (gwb + 3 < DIM);
    const int jc0 = min(max(gwb + 0, 0), DIM - 1);
    const int jc1 = min(max(gwb + 1, 0), DIM - 1);
    const int jc2 = min(max(gwb + 2, 0), DIM - 1);
    const int jc3 = min(max(gwb + 3, 0), DIM - 1);

    auto load4 = [&](const float* sl) -> float4 {
        const float* row = sl + (size_t)gh * DIM;
        if (fast) return *reinterpret_cast<const float4*>(row + gwb);
        float4 r;
        r.x = row[jc0]; r.y = row[jc1]; r.z = row[jc2]; r.w = row[jc3];
        return r;
    };

    // ---- stage2 role: (channel c2, w-group w42, row-quad i02) ----
    const int c2  = t / 24;               // 0..4 for t<120
    const int r2  = t - c2 * 24;
    const int w42 = r2 >> 2;              // 0..5
    const int i02 = (r2 & 3) * 4;         // 0,4,8,12

    // ---- stage3 role: (row i3, w-group j3) ----
    const int i3 = t >> 2;                // 0..15 for t<64
    const int j3 = (t & 3) * 4;           // 0,4,8,12

    // ---- stage4 role: one output column each ----
    const int i4 = t >> 4;
    const int j4 = t & 15;

    float hist[9][5];                     // register ring (constant indices)
    float rs[5] = {0.f, 0.f, 0.f, 0.f, 0.f};
    float acc = 0.f;

    // prefetch first slice
    float4 xv = {0,0,0,0}, yv = {0,0,0,0};
    {
        const int z0 = min(max(zo0 - 4, 0), DIM - 1);
        if (t < 144) {
            xv = load4(xb + (size_t)z0 * SLICE);
            yv = load4(yb + (size_t)z0 * SLICE);
        }
    }

    const int zlast = zo0 + CD + 3;       // 48 input slices: zo0-4 .. zlast
    for (int base = zo0 - 4; base <= zlast; base += 9) {
        #pragma unroll
        for (int p = 0; p < 9; ++p) {
            const int zi = base + p;      // phase (zi - (zo0-4)) % 9 == p
            if (zi <= zlast) {
                // stage1: products of prefetched slice -> S
                if (t < 144) {
                    const int jw = 4 * w41;
                    *reinterpret_cast<float4*>(&S[SIDX(0, h1, jw)]) = xv;
                    *reinterpret_cast<float4*>(&S[SIDX(1, h1, jw)]) = yv;
                    *reinterpret_cast<float4*>(&S[SIDX(2, h1, jw)]) = xv * xv;
                    *reinterpret_cast<float4*>(&S[SIDX(3, h1, jw)]) = yv * yv;
                    *reinterpret_cast<float4*>(&S[SIDX(4, h1, jw)]) = xv * yv;
                }
                __syncthreads();

                // prefetch next slice (consumed next iteration, after 2 bars)
                if (t < 144 && zi < zlast) {
                    const int zn = min(max(zi + 1, 0), DIM - 1);
                    xv = load4(xb + (size_t)zn * SLICE);
                    yv = load4(yb + (size_t)zn * SLICE);
                }

                // stage2: 9-tap h-sum S->T (b128 slide over 4 rows)
                if (t < 120) {
                    const int jw = 4 * w42;
                    float4 s = {0,0,0,0};
                    #pragma unroll
                    for (int k = 0; k < 9; ++k)
                        s += *reinterpret_cast<const float4*>(&S[SIDX(c2, i02 + k, jw)]);
                    *reinterpret_cast<float4*>(&T[TIDX(c2, i02, jw)]) = s;
                    #pragma unroll
                    for (int m = 1; m < 4; ++m) {
                        s += *reinterpret_cast<const float4*>(&S[SIDX(c2, i02 + 8 + m, jw)])
                           - *reinterpret_cast<const float4*>(&S[SIDX(c2, i02 + m - 1, jw)]);
                        *reinterpret_cast<float4*>(&T[TIDX(c2, i02 + m, jw)]) = s;
                    }
                }
                __syncthreads();

                // stage3: 9-tap w-sum T->U (b128 slide, 1 wave)
                if (t < 64) {
                    #pragma unroll
                    for (int c = 0; c < 5; ++c) {
                        const float4 t0 = *reinterpret_cast<const float4*>(&T[TIDX(c, i3, j3)]);
                        const float4 t1 = *reinterpret_cast<const float4*>(&T[TIDX(c, i3, j3 + 4)]);
                        const float4 t2 = *reinterpret_cast<const float4*>(&T[TIDX(c, i3, j3 + 8)]);
                        float4 uo;
                        float s = t0.x + t0.y + t0.z + t0.w
                                + t1.x + t1.y + t1.z + t1.w + t2.x;
                        uo.x = s;
                        s += t2.y - t0.x; uo.y = s;
                        s += t2.z - t0.y; uo.z = s;
                        s += t2.w - t0.z; uo.w = s;
                        *reinterpret_cast<float4*>(&U[UIDX(c, i3, j3)]) = uo;
                    }
                }
                __syncthreads();

                // stage4: register d-ring update + ncc emit
                float u[5];
                #pragma unroll
                for (int c = 0; c < 5; ++c) {
                    u[c] = U[UIDX(c, i4, j4)];
                    rs[c] += u[c];
                    hist[p][c] = u[c];
                }
                if (zi >= zo0 + 4) {
                    const float inv = 1.0f / 729.0f;
                    const float xm = rs[0] * inv, ym = rs[1] * inv;
                    const float x2 = rs[2] * inv, y2 = rs[3] * inv;
                    const float xy = rs[4] * inv;
                    const float cross = xy - xm * ym;
                    const float vx = x2 - xm * xm;
                    const float vy = y2 - ym * ym;
                    acc += cross * cross / (vx * vy + 1e-5f);
                    const int po = (p + 1) % 9;    // slice zi-8 leaves window
                    #pragma unroll
                    for (int c = 0; c < 5; ++c)
                        rs[c] -= hist[po][c];
                }
                // stage4 U-reads are ordered before next slice's U-writes by
                // the next iteration's bar1+bar2
            }
        }
    }

    // ---- block reduction: wave shuffle, then 4 partials via LDS ----
    #pragma unroll
    for (int off = 32; off > 0; off >>= 1)
        acc += __shfl_down(acc, off, 64);
    const int wave = t >> 6;
    if ((t & 63) == 0) wsum[wave] = acc;
    __syncthreads();
    if (t == 0) {
        const float s = wsum[0] + wsum[1] + wsum[2] + wsum[3];
        atomicAdd(out, -s * (1.0f / 8192000.0f));
    }
}

extern "C" void kernel_launch(void* const* d_in, const int* in_sizes, int n_in,
                              void* d_out, int out_size, void* d_ws, size_t ws_size,
                              hipStream_t stream)
{
    const float* x = (const float*)d_in[0];
    const float* y = (const float*)d_in[1];
    float* out = (float*)d_out;

    // d_out is poisoned 0xAA before every call; accumulate atomically on zero
    hipMemsetAsync(out, 0, sizeof(float), stream);

    dim3 grid(DIM / TW, DIM / TH, 2 * (DIM / CD));  // 10 x 10 x 8 = 800 blocks
    lncc_kernel<<<grid, 256, 0, stream>>>(x, y, out);
}